// Round 1
// baseline (226.304 us; speedup 1.0000x reference)
//
#include <hip/hip_runtime.h>
#include <hip/hip_fp16.h>

// ---------------------------------------------------------------------------
// 3-layer GCN, CSR-gather, fp16 dataflow + MFMA GEMM, fused pipeline R18:
//   zero+wcast:   cnt=0  ||  Wt1/Wt2 cast                    (drops memset)
//   count+gemm1:  cnt histogram (stores per-edge rank) || HWS1 = half(x@W1)
//                 [GEMM1 decoupled from dis -> overlaps the whole CSR chain]
//   scan x2:      row_ptr + dis = rsqrt(deg)
//   bin+scale:    atomic-free CSR binning via rank || HWS1 *= dis (row scale)
//   sortrows:     per-row ascending sort of src lists (32-lane odd-even).
//                 Sum is commutative -> any permutation correct. Purpose:
//                 concurrent quarter-waves sweep src ascending together ->
//                 instantaneous gather window ~2-4MB fits per-XCD L2.
//   gather+gemm2: h1 = relu(dis*S HWS1 + b1) -> LDS -> HWS2 = half(dis*(h1@W2))
//   gather+gemv:  hw3s = dis * dot(relu(dis*S HWS2 + b2), W3)
//   gather3:      out = relu(dis*S hw3s + b3)
// Lessons: R4/R5 never force min-waves. R7/R8/R16: gather is scattered-
// REQUEST-rate bound (bytes halved -> ~no change). R13: keep hot kernels
// VGPR<64. R14/R15: rank trick. R17: quarter-wave gather (4 rows/wave-load).
// R18 (this): critical-path overlap + src-sorted rows for L2 sweep locality.
// ---------------------------------------------------------------------------

typedef _Float16 v8h __attribute__((ext_vector_type(8)));
typedef float v4f __attribute__((ext_vector_type(4)));

// fused: zero cnt (blocks [0,BZ)) + weight cast (blocks >= BZ)
__global__ __launch_bounds__(256) void k_zero_wcast(int* __restrict__ cnt, int nN,
                                                    int BZ,
                                                    const float* __restrict__ W1,
                                                    const float* __restrict__ W2,
                                                    __half* __restrict__ Wt1,
                                                    __half* __restrict__ Wt2) {
    int b = blockIdx.x;
    if (b < BZ) {
        int i = b * 256 + threadIdx.x;
        if (i < nN) cnt[i] = 0;
    } else {
        int i = (b - BZ) * 256 + threadIdx.x;   // 0..16383
        int k = i >> 7, c = i & 127;
        Wt1[c * 128 + k] = __float2half(W1[i]);
        Wt2[c * 128 + k] = __float2half(W2[i]);
    }
}

// FUSED dispatch: blocks [0,BE) = edge count + rank record; blocks >= BE =
// layer-1 MFMA GEMM *without* dis folding (dis not known yet -> full overlap
// of GEMM1 with the count pass; dis applied later by the scale pass).
__global__ __launch_bounds__(256) void k_count_gemm(const int* __restrict__ dst,
                                                    int* __restrict__ cnt,
                                                    int* __restrict__ rank, int nE,
                                                    int BE,
                                                    const float* __restrict__ X32,
                                                    const __half* __restrict__ Wt,
                                                    __half* __restrict__ HWS,
                                                    int nrows) {
    __shared__ __half xs[64 * 136];
    if (blockIdx.x < BE) {
        int e = blockIdx.x * 256 + threadIdx.x;
        if (e < nE) rank[e] = atomicAdd(&cnt[dst[e]], 1);
        return;
    }

    // --- GEMM path: HWS = half(x @ W1) ---
    const int t = threadIdx.x;
    const int row0 = (blockIdx.x - BE) * 64;

#pragma unroll
    for (int i = 0; i < 8; ++i) {
        int f = t + i * 256;
        int r = f >> 5, k4 = f & 31;
        int gr = row0 + r;
        float4 v = make_float4(0.f, 0.f, 0.f, 0.f);
        if (gr < nrows) v = ((const float4*)X32)[(size_t)gr * 32 + k4];
        __half2 h01 = __float22half2_rn(make_float2(v.x, v.y));
        __half2 h23 = __float22half2_rn(make_float2(v.z, v.w));
        float2 packed;
        *(__half2*)&packed.x = h01;
        *(__half2*)&packed.y = h23;
        *(float2*)&xs[r * 136 + k4 * 4] = packed;
    }
    __syncthreads();

    const int w = t >> 6;
    const int l = t & 63;
    const int mrow = l & 15;
    const int kq = l >> 4;

    v8h a[4];
#pragma unroll
    for (int kk = 0; kk < 4; ++kk)
        a[kk] = *(const v8h*)&xs[(w * 16 + mrow) * 136 + kk * 32 + kq * 8];

    v4f acc[8];
#pragma unroll
    for (int c = 0; c < 8; ++c) acc[c] = (v4f){0.f, 0.f, 0.f, 0.f};

#pragma unroll
    for (int kk = 0; kk < 4; ++kk) {
#pragma unroll
        for (int c = 0; c < 8; ++c) {
            v8h b = *(const v8h*)&Wt[(size_t)(c * 16 + mrow) * 128 + kk * 32 + kq * 8];
            acc[c] = __builtin_amdgcn_mfma_f32_16x16x32_f16(a[kk], b, acc[c], 0, 0, 0);
        }
    }

#pragma unroll
    for (int c = 0; c < 8; ++c) {
#pragma unroll
        for (int r = 0; r < 4; ++r) {
            int grow = row0 + w * 16 + kq * 4 + r;
            if (grow < nrows)
                HWS[(size_t)grow * 128 + c * 16 + mrow] = __float2half(acc[c][r]);
        }
    }
}

// scan stage 1 + fused dis = rsqrt(cnt+1)
__global__ __launch_bounds__(256) void k_scan_blk(const int* __restrict__ cnt,
                                                  float* __restrict__ dis,
                                                  int* __restrict__ excl,
                                                  int* __restrict__ blk_sum, int nN) {
    __shared__ int sm[256];
    const int t = threadIdx.x;
    int i = blockIdx.x * 256 + t;
    int v = (i < nN) ? cnt[i] : 0;
    if (i < nN) dis[i] = rsqrtf((float)v + 1.0f);
    sm[t] = v;
    __syncthreads();
#pragma unroll
    for (int off = 1; off < 256; off <<= 1) {
        int x = (t >= off) ? sm[t - off] : 0;
        __syncthreads();
        sm[t] += x;
        __syncthreads();
    }
    if (i < nN) excl[i] = sm[t] - v;
    if (t == 255) blk_sum[blockIdx.x] = sm[255];
}

// stage 2+3 fused: every block scans blk_sum (nB<=256) in LDS, then adds.
__global__ __launch_bounds__(256) void k_scan_add(const int* __restrict__ excl,
                                                  const int* __restrict__ blk_sum,
                                                  int* __restrict__ row_ptr,
                                                  int nN, int nB) {
    __shared__ int sm[256];
    const int t = threadIdx.x;
    int v = (t < nB) ? blk_sum[t] : 0;
    sm[t] = v;
    __syncthreads();
#pragma unroll
    for (int off = 1; off < 256; off <<= 1) {
        int x = (t >= off) ? sm[t - off] : 0;
        __syncthreads();
        sm[t] += x;
        __syncthreads();
    }
    int i = blockIdx.x * 256 + t;
    if (i < nN) {
        int b = i >> 8;
        row_ptr[i] = excl[i] + sm[b] - blk_sum[b];
    }
    if (i == 0) row_ptr[nN] = sm[255];
}

// FUSED dispatch: blocks [0,BE) = atomic-free CSR binning via rank;
// blocks >= BE = HWS1 row scale by dis (restores the dis*(x@W1) semantics
// that GEMM1 no longer applies). float4 = 8 halves per thread, coalesced.
__global__ __launch_bounds__(256) void k_bin_scale(const int* __restrict__ src,
                                                   const int* __restrict__ dst,
                                                   const int* __restrict__ rank,
                                                   const int* __restrict__ row_ptr,
                                                   int* __restrict__ src_csr, int nE,
                                                   int BE,
                                                   const float* __restrict__ dis,
                                                   __half* __restrict__ HWS, int nN) {
    int b = blockIdx.x;
    if (b < BE) {
        int e = b * 256 + threadIdx.x;
        if (e < nE) {
            int d = dst[e];
            src_csr[row_ptr[d] + rank[e]] = src[e];
        }
        return;
    }
    int i = (b - BE) * 256 + threadIdx.x;     // over nN*16 float4s
    if (i < nN * 16) {
        int g = i >> 4;
        float dn = dis[g];
        float4 v = ((const float4*)HWS)[i];
        __half2* hp = (__half2*)&v;
#pragma unroll
        for (int k = 0; k < 4; ++k) {
            float2 f = __half22float2(hp[k]);
            hp[k] = __float22half2_rn(make_float2(f.x * dn, f.y * dn));
        }
        ((float4*)HWS)[i] = v;
    }
}

// per-row ascending sort of src lists: 32-lane odd-even transposition via
// shuffles (one half-wave per row, 8 rows per 256-thr block). Rows with
// degree > 32 are left unsorted (correctness unaffected; vanishingly rare
// at Poisson(12)). Goal: all concurrent gathers sweep src in the same
// ascending order -> moving L2-resident window instead of full-buffer random.
__global__ __launch_bounds__(256) void k_sortrows(const int* __restrict__ row_ptr,
                                                  int* __restrict__ src_csr, int nN) {
    int r = blockIdx.x * 8 + (threadIdx.x >> 5);
    if (r >= nN) return;
    const int l = threadIdx.x & 31;
    int beg = row_ptr[r], end = row_ptr[r + 1];
    int n = end - beg;
    if (n <= 1 || n > 32) return;
    int v = (l < n) ? src_csr[beg + l] : 0x7fffffff;
#pragma unroll
    for (int p = 0; p < 32; ++p) {
        bool up = ((l + p) & 1) == 0;         // pair with l+1 if up else l-1
        int partner = up ? l + 1 : l - 1;
        if (partner < 0) partner = 0;
        if (partner > 31) partner = 31;
        int o = __shfl(v, partner, 32);
        if (partner != l) v = up ? min(v, o) : max(v, o);
    }
    if (l < n) src_csr[beg + l] = v;
}

// add 8 halves (packed in a float4) into acc[8] (fp32)
__device__ __forceinline__ void add8(float acc[8], float4 r) {
    __half2* hp = (__half2*)&r;
#pragma unroll
    for (int k = 0; k < 4; ++k) {
        float2 f = __half22float2(hp[k]);
        acc[2 * k] += f.x;
        acc[2 * k + 1] += f.y;
    }
}

// QUARTER-WAVE gather: 16 lanes per node row, 16B (8 halves) per lane.
// One wave-load instruction covers 4 node rows (1KB). acc[8] fp32, incl self.
__device__ __forceinline__ void gather_row16(const float4* __restrict__ Hv,
                                             const int* __restrict__ row_ptr,
                                             const int* __restrict__ src_csr,
                                             int g, int f8, float acc[8]) {
    int beg = row_ptr[g], end = row_ptr[g + 1];
#pragma unroll
    for (int k = 0; k < 8; ++k) acc[k] = 0.f;
    add8(acc, Hv[(size_t)g * 16 + f8]);   // self term
    int e = beg;
    for (; e + 4 <= end; e += 4) {        // 4-deep batch: r[4]x4 = 16 VGPRs
        int s[4];
#pragma unroll
        for (int j = 0; j < 4; ++j) s[j] = src_csr[e + j];
        float4 r[4];
#pragma unroll
        for (int j = 0; j < 4; ++j) r[j] = Hv[(size_t)s[j] * 16 + f8];
#pragma unroll
        for (int j = 0; j < 4; ++j) add8(acc, r[j]);
    }
    for (; e < end; ++e) add8(acc, Hv[(size_t)src_csr[e] * 16 + f8]);
}

// FUSED layer-1 gather + layer-2 GEMM, 512 threads.
//   phase 1: 32 quarter-waves pull node slots from an LDS queue; each gathers
//            a full 128-col row with 16 lanes x 16B (4 rows per wave-load).
//   phase 2: 8 MFMA waves; wave w: rows (w&3)*16..+16, col-tiles (w>>2)*4..+4
__global__ __launch_bounds__(512) void k_gather_gemm(const __half* __restrict__ HWS1,
                                                     const int* __restrict__ row_ptr,
                                                     const int* __restrict__ src_csr,
                                                     const float* __restrict__ dis,
                                                     const float* __restrict__ bias,
                                                     const __half* __restrict__ Wt,
                                                     __half* __restrict__ HWS2,
                                                     int nN) {
    __shared__ __half xs[64 * 136];
    __shared__ int q;
    const int t = threadIdx.x;
    const int row0 = blockIdx.x * 64;
    const int l = t & 63;
    const int f8 = t & 15;            // lane within quarter-wave
    const int qbase = l & 48;         // base lane of this quarter in the wave
    const float4* Hv = (const float4*)HWS1;

    float bv[8];
    *(float4*)&bv[0] = ((const float4*)bias)[f8 * 2];
    *(float4*)&bv[4] = ((const float4*)bias)[f8 * 2 + 1];

    if (t == 0) q = 0;
    __syncthreads();

    for (;;) {
        int lr = 0;
        if (f8 == 0) lr = atomicAdd(&q, 1);
        lr = __shfl(lr, qbase, 64);
        if (lr >= 64) break;
        int g = row0 + lr;
        float acc[8];
        __half2 h[4];
        if (g < nN) {
            gather_row16(Hv, row_ptr, src_csr, g, f8, acc);
            float dn = dis[g];
#pragma unroll
            for (int k = 0; k < 4; ++k)
                h[k] = __float22half2_rn(make_float2(
                    fmaxf(acc[2 * k] * dn + bv[2 * k], 0.f),
                    fmaxf(acc[2 * k + 1] * dn + bv[2 * k + 1], 0.f)));
        } else {
#pragma unroll
            for (int k = 0; k < 4; ++k) h[k] = __float2half2_rn(0.f);
        }
        *(float4*)&xs[lr * 136 + f8 * 8] = *(float4*)h;   // 16B ds_write_b128
    }
    __syncthreads();

    const int w = t >> 6;        // wave 0..7
    const int mrow = l & 15;
    const int kq = l >> 4;
    const int rgrp = (w & 3) * 16;   // row group
    const int cgrp = (w >> 2) * 4;   // col-tile group (4 tiles of 16)

    v8h a[4];
#pragma unroll
    for (int kk = 0; kk < 4; ++kk)
        a[kk] = *(const v8h*)&xs[(rgrp + mrow) * 136 + kk * 32 + kq * 8];

    v4f acc[4];
#pragma unroll
    for (int c = 0; c < 4; ++c) acc[c] = (v4f){0.f, 0.f, 0.f, 0.f};

#pragma unroll
    for (int kk = 0; kk < 4; ++kk) {
#pragma unroll
        for (int c = 0; c < 4; ++c) {
            v8h b = *(const v8h*)&Wt[(size_t)((cgrp + c) * 16 + mrow) * 128 + kk * 32 + kq * 8];
            acc[c] = __builtin_amdgcn_mfma_f32_16x16x32_f16(a[kk], b, acc[c], 0, 0, 0);
        }
    }

    float dn4[4];
#pragma unroll
    for (int r = 0; r < 4; ++r) {
        int grow = row0 + rgrp + kq * 4 + r;
        dn4[r] = (grow < nN) ? dis[grow] : 0.f;
    }
#pragma unroll
    for (int c = 0; c < 4; ++c) {
#pragma unroll
        for (int r = 0; r < 4; ++r) {
            int grow = row0 + rgrp + kq * 4 + r;
            if (grow < nN)
                HWS2[(size_t)grow * 128 + (cgrp + c) * 16 + mrow] =
                    __float2half(acc[c][r] * dn4[r]);
        }
    }
}

// FUSED layer-2 gather + layer-3 gemv (quarter-wave gather, 16 nodes/block):
//   hw3s[g] = dis[g] * dot(relu(dis[g]*S HWS2 + b2), W3)
__global__ __launch_bounds__(256) void k_gather_gemv(const __half* __restrict__ HWS2,
                                                     const int* __restrict__ row_ptr,
                                                     const int* __restrict__ src_csr,
                                                     const float* __restrict__ dis,
                                                     const float* __restrict__ bias,
                                                     const float* __restrict__ W3,
                                                     float* __restrict__ hw3s, int nN) {
    int g = blockIdx.x * 16 + (threadIdx.x >> 4);
    if (g >= nN) return;
    int f8 = threadIdx.x & 15;
    float acc[8];
    gather_row16((const float4*)HWS2, row_ptr, src_csr, g, f8, acc);
    float dn = dis[g];
    float bv[8], w3[8];
    *(float4*)&bv[0] = ((const float4*)bias)[f8 * 2];
    *(float4*)&bv[4] = ((const float4*)bias)[f8 * 2 + 1];
    *(float4*)&w3[0] = ((const float4*)W3)[f8 * 2];
    *(float4*)&w3[4] = ((const float4*)W3)[f8 * 2 + 1];
    float sum = 0.f;
#pragma unroll
    for (int k = 0; k < 8; ++k)
        sum += fmaxf(acc[k] * dn + bv[k], 0.f) * w3[k];
#pragma unroll
    for (int off = 8; off > 0; off >>= 1) sum += __shfl_down(sum, off, 16);
    if (f8 == 0) hw3s[g] = sum * dn;
}

// scalar pull-aggregation + final relu -> d_out
__global__ __launch_bounds__(256) void k_gather3(const float* __restrict__ hw3s,
                                                 const int* __restrict__ row_ptr,
                                                 const int* __restrict__ src_csr,
                                                 const float* __restrict__ dis,
                                                 const float* __restrict__ b3,
                                                 float* __restrict__ out, int nN) {
    int i = blockIdx.x * 256 + threadIdx.x;
    if (i >= nN) return;
    float acc = hw3s[i];
    int beg = row_ptr[i], end = row_ptr[i + 1];
    for (int e = beg; e < end; ++e) acc += hw3s[src_csr[e]];
    out[i] = fmaxf(acc * dis[i] + b3[0], 0.f);
}

extern "C" void kernel_launch(void* const* d_in, const int* in_sizes, int n_in,
                              void* d_out, int out_size, void* d_ws, size_t ws_size,
                              hipStream_t stream) {
    const float* x  = (const float*)d_in[0];
    const int*   ei = (const int*)d_in[1];
    const float* W1 = (const float*)d_in[2];
    const float* b1 = (const float*)d_in[3];
    const float* W2 = (const float*)d_in[4];
    const float* b2 = (const float*)d_in[5];
    const float* W3 = (const float*)d_in[6];
    const float* b3 = (const float*)d_in[7];

    const int nN = in_sizes[0] / 128;
    const int nE = in_sizes[1] / 2;
    const int* src = ei;
    const int* dst = ei + nE;

    const int nB = (nN + 255) / 256;   // scan blocks (<=256)

    // workspace layout
    char* p = (char*)d_ws;
    int*    cnt      = (int*)p;           p += (size_t)nN * 4;
    int*    excl     = (int*)p;           p += (size_t)nN * 4;
    int*    blk_sum  = (int*)p;           p += (size_t)(nB + 1) * 4;
    int*    row_ptr  = (int*)p;           p += (size_t)(nN + 1) * 4;
    int*    rank     = (int*)p;           p += (size_t)nE * 4;
    int*    src_csr  = (int*)p;           p += (size_t)nE * 4;
    float*  dis      = (float*)p;         p += (size_t)nN * 4;
    float*  hw3s     = (float*)p;         p += (size_t)nN * 4;
    p = (char*)(((uintptr_t)p + 255) & ~(uintptr_t)255);
    __half* Wt1      = (__half*)p;        p += (size_t)128 * 128 * 2;
    __half* Wt2      = (__half*)p;        p += (size_t)128 * 128 * 2;
    __half* bufA     = (__half*)p;        p += (size_t)nN * 128 * 2;  // HWS1
    p = (char*)(((uintptr_t)p + 255) & ~(uintptr_t)255);
    __half* bufB     = (__half*)p;        p += (size_t)nN * 128 * 2;  // HWS2

    const int BE  = (nE + 255) / 256;            // 2344
    const int BN  = (nN + 255) / 256;            // 196
    const int BG  = (nN + 63) / 64;              // 782
    const int BGV = (nN + 15) / 16;              // 3125
    const int BSC = (nN * 16 + 255) / 256;       // 3125 (scale pass)
    const int BSR = (nN + 7) / 8;                // 6250 (row sort)

    // --- cnt zero + weight cast (one dispatch, replaces hipMemsetAsync) ---
    k_zero_wcast<<<BN + 64, 256, 0, stream>>>(cnt, nN, BN, W1, W2, Wt1, Wt2);

    // --- edge count/rank OVERLAPPED with layer-1 GEMM (dis-free) ---
    k_count_gemm<<<BE + BG, 256, 0, stream>>>(dst, cnt, rank, nE, BE,
                                              x, Wt1, bufA, nN);

    // --- CSR scan + norms ---
    k_scan_blk<<<nB, 256, 0, stream>>>(cnt, dis, excl, blk_sum, nN);
    k_scan_add<<<nB, 256, 0, stream>>>(excl, blk_sum, row_ptr, nN, nB);

    // --- atomic-free binning OVERLAPPED with HWS1 *= dis scale pass ---
    k_bin_scale<<<BE + BSC, 256, 0, stream>>>(src, dst, rank, row_ptr, src_csr,
                                              nE, BE, dis, bufA, nN);

    // --- per-row src sort for gather L2 sweep locality ---
    k_sortrows<<<BSR, 256, 0, stream>>>(row_ptr, src_csr, nN);

    // --- fused layer-1 gather + layer-2 GEMM: HWS1 -> HWS2 (512 thr) ---
    k_gather_gemm<<<BG, 512, 0, stream>>>(bufA, row_ptr, src_csr, dis, b1, Wt2,
                                          bufB, nN);

    // --- fused layer-2 gather + layer-3 gemv: HWS2 -> hw3s ---
    k_gather_gemv<<<BGV, 256, 0, stream>>>(bufB, row_ptr, src_csr, dis, b2, W3,
                                           hw3s, nN);

    // --- layer-3 scalar gather -> d_out ---
    k_gather3<<<BN, 256, 0, stream>>>(hw3s, row_ptr, src_csr, dis, b3,
                                      (float*)d_out, nN);
}

// Round 2
// 222.553 us; speedup vs baseline: 1.0169x; 1.0169x over previous
//
#include <hip/hip_runtime.h>
#include <hip/hip_fp16.h>

// ---------------------------------------------------------------------------
// 3-layer GCN, CSR-gather, fp16 dataflow + MFMA GEMM, fused pipeline R19:
//   zero+wcast:   cnt8=0  ||  Wt1/Wt2 cast
//   count+gemm1:  8-BANK cnt histogram (bank=blockIdx&7 ~ XCD id; kills the
//                 64B-line ping-pong of device atomics across XCD L2s; rank
//                 recorded per (bank,dst)) || HWS1 = half(x@W1), dis-free.
//   scan x2:      row_ptr (deg = sum of 8 banks) + dis + per-bank base8
//   bin:          atomic-free CSR binning: pos = base8[d*8+bank(e)] + rank[e]
//   gather+gemm2: h1 = relu(dis*S dis[s]*HWS1[s] + b1) [dis[s] folded as FMA
//                 during gather] -> LDS -> HWS2 = half(dis*(h1@W2))
//   gather+gemv:  hw3s = dis * dot(relu(dis*S HWS2 + b2), W3)
//   gather3:      out = relu(dis*S hw3s + b3)
// Lessons: R4/R5 never force min-waves. R7/R8/R16: gather is scattered-
// REQUEST-rate bound. R13: VGPR<64 for hot kernels. R14/R15: rank trick.
// R17: quarter-wave gather. R18 FAILED: per-row src sort gives no locality
// (12 sorted uniform draws still span the full range; concurrent waves are at
// unrelated rows) and the HWS1 scale pass was critical-path cost. R19: 8-bank
// privatized count (atomic line ping-pong theory) + dis[s]-as-FMA in gather.
// ---------------------------------------------------------------------------

typedef _Float16 v8h __attribute__((ext_vector_type(8)));
typedef float v4f __attribute__((ext_vector_type(4)));

// fused: zero cnt8 (blocks [0,BZ)) + weight cast (blocks >= BZ)
__global__ __launch_bounds__(256) void k_zero_wcast(int* __restrict__ cnt8, int n8,
                                                    int BZ,
                                                    const float* __restrict__ W1,
                                                    const float* __restrict__ W2,
                                                    __half* __restrict__ Wt1,
                                                    __half* __restrict__ Wt2) {
    int b = blockIdx.x;
    if (b < BZ) {
        int i = b * 256 + threadIdx.x;
        if (i < n8) cnt8[i] = 0;
    } else {
        int i = (b - BZ) * 256 + threadIdx.x;   // 0..16383
        int k = i >> 7, c = i & 127;
        Wt1[c * 128 + k] = __float2half(W1[i]);
        Wt2[c * 128 + k] = __float2half(W2[i]);
    }
}

// FUSED dispatch: blocks [0,BE) = 8-bank edge count + rank record; blocks
// >= BE = layer-1 MFMA GEMM (dis-free -> overlaps the whole CSR chain).
// bank = blockIdx&7: consecutive blocks round-robin XCDs, so each bank's
// counter array stays in one XCD's L2 -> no cross-XCD 64B line migration.
__global__ __launch_bounds__(256) void k_count_gemm(const int* __restrict__ dst,
                                                    int* __restrict__ cnt8,
                                                    int* __restrict__ rank, int nE,
                                                    int BE, int nN,
                                                    const float* __restrict__ X32,
                                                    const __half* __restrict__ Wt,
                                                    __half* __restrict__ HWS,
                                                    int nrows) {
    __shared__ __half xs[64 * 136];
    if (blockIdx.x < BE) {
        int e = blockIdx.x * 256 + threadIdx.x;
        if (e < nE) {
            int bank = blockIdx.x & 7;
            rank[e] = atomicAdd(&cnt8[bank * nN + dst[e]], 1);
        }
        return;
    }

    // --- GEMM path: HWS = half(x @ W1) ---
    const int t = threadIdx.x;
    const int row0 = (blockIdx.x - BE) * 64;

#pragma unroll
    for (int i = 0; i < 8; ++i) {
        int f = t + i * 256;
        int r = f >> 5, k4 = f & 31;
        int gr = row0 + r;
        float4 v = make_float4(0.f, 0.f, 0.f, 0.f);
        if (gr < nrows) v = ((const float4*)X32)[(size_t)gr * 32 + k4];
        __half2 h01 = __float22half2_rn(make_float2(v.x, v.y));
        __half2 h23 = __float22half2_rn(make_float2(v.z, v.w));
        float2 packed;
        *(__half2*)&packed.x = h01;
        *(__half2*)&packed.y = h23;
        *(float2*)&xs[r * 136 + k4 * 4] = packed;
    }
    __syncthreads();

    const int w = t >> 6;
    const int l = t & 63;
    const int mrow = l & 15;
    const int kq = l >> 4;

    v8h a[4];
#pragma unroll
    for (int kk = 0; kk < 4; ++kk)
        a[kk] = *(const v8h*)&xs[(w * 16 + mrow) * 136 + kk * 32 + kq * 8];

    v4f acc[8];
#pragma unroll
    for (int c = 0; c < 8; ++c) acc[c] = (v4f){0.f, 0.f, 0.f, 0.f};

#pragma unroll
    for (int kk = 0; kk < 4; ++kk) {
#pragma unroll
        for (int c = 0; c < 8; ++c) {
            v8h b = *(const v8h*)&Wt[(size_t)(c * 16 + mrow) * 128 + kk * 32 + kq * 8];
            acc[c] = __builtin_amdgcn_mfma_f32_16x16x32_f16(a[kk], b, acc[c], 0, 0, 0);
        }
    }

#pragma unroll
    for (int c = 0; c < 8; ++c) {
#pragma unroll
        for (int r = 0; r < 4; ++r) {
            int grow = row0 + w * 16 + kq * 4 + r;
            if (grow < nrows)
                HWS[(size_t)grow * 128 + c * 16 + mrow] = __float2half(acc[c][r]);
        }
    }
}

// scan stage 1: deg = sum of 8 banks, fused dis = rsqrt(deg+1)
__global__ __launch_bounds__(256) void k_scan_blk(const int* __restrict__ cnt8,
                                                  float* __restrict__ dis,
                                                  int* __restrict__ excl,
                                                  int* __restrict__ blk_sum, int nN) {
    __shared__ int sm[256];
    const int t = threadIdx.x;
    int i = blockIdx.x * 256 + t;
    int v = 0;
    if (i < nN) {
#pragma unroll
        for (int b = 0; b < 8; ++b) v += cnt8[b * nN + i];
        dis[i] = rsqrtf((float)v + 1.0f);
    }
    sm[t] = v;
    __syncthreads();
#pragma unroll
    for (int off = 1; off < 256; off <<= 1) {
        int x = (t >= off) ? sm[t - off] : 0;
        __syncthreads();
        sm[t] += x;
        __syncthreads();
    }
    if (i < nN) excl[i] = sm[t] - v;
    if (t == 255) blk_sum[blockIdx.x] = sm[255];
}

// stage 2+3 fused + per-bank base emission:
// base8[i*8+b] = row_ptr[i] + sum_{b'<b} cnt8[b'][i]
__global__ __launch_bounds__(256) void k_scan_add(const int* __restrict__ excl,
                                                  const int* __restrict__ blk_sum,
                                                  const int* __restrict__ cnt8,
                                                  int* __restrict__ row_ptr,
                                                  int* __restrict__ base8,
                                                  int nN, int nB) {
    __shared__ int sm[256];
    const int t = threadIdx.x;
    int v = (t < nB) ? blk_sum[t] : 0;
    sm[t] = v;
    __syncthreads();
#pragma unroll
    for (int off = 1; off < 256; off <<= 1) {
        int x = (t >= off) ? sm[t - off] : 0;
        __syncthreads();
        sm[t] += x;
        __syncthreads();
    }
    int i = blockIdx.x * 256 + t;
    if (i < nN) {
        int b = i >> 8;
        int rp = excl[i] + sm[b] - blk_sum[b];
        row_ptr[i] = rp;
        int off = rp;
#pragma unroll
        for (int bk = 0; bk < 8; ++bk) {
            base8[i * 8 + bk] = off;
            off += cnt8[bk * nN + i];
        }
    }
    if (i == 0) row_ptr[nN] = sm[255];
}

// atomic-free CSR binning: bank(e) recomputed = blockIdx&7 (same mapping as
// count since both use e = blockIdx*256+t over the identical block range).
__global__ __launch_bounds__(256) void k_bin(const int* __restrict__ src,
                                             const int* __restrict__ dst,
                                             const int* __restrict__ rank,
                                             const int* __restrict__ base8,
                                             int* __restrict__ src_csr, int nE) {
    int e = blockIdx.x * 256 + threadIdx.x;
    if (e < nE) {
        int d = dst[e];
        int bank = blockIdx.x & 7;
        src_csr[base8[d * 8 + bank] + rank[e]] = src[e];
    }
}

// add 8 halves (packed in a float4) into acc[8] (fp32)
__device__ __forceinline__ void add8(float acc[8], float4 r) {
    __half2* hp = (__half2*)&r;
#pragma unroll
    for (int k = 0; k < 4; ++k) {
        float2 f = __half22float2(hp[k]);
        acc[2 * k] += f.x;
        acc[2 * k + 1] += f.y;
    }
}

// weighted add: acc[k] += f * w  (FMA -> same instruction count as add8)
__device__ __forceinline__ void add8w(float acc[8], float4 r, float w) {
    __half2* hp = (__half2*)&r;
#pragma unroll
    for (int k = 0; k < 4; ++k) {
        float2 f = __half22float2(hp[k]);
        acc[2 * k] = fmaf(f.x, w, acc[2 * k]);
        acc[2 * k + 1] = fmaf(f.y, w, acc[2 * k + 1]);
    }
}

// QUARTER-WAVE gather: 16 lanes per node row, 16B (8 halves) per lane.
// Plain version (rows pre-scaled by dis[s]); acc includes self term.
__device__ __forceinline__ void gather_row16(const float4* __restrict__ Hv,
                                             const int* __restrict__ row_ptr,
                                             const int* __restrict__ src_csr,
                                             int g, int f8, float acc[8]) {
    int beg = row_ptr[g], end = row_ptr[g + 1];
#pragma unroll
    for (int k = 0; k < 8; ++k) acc[k] = 0.f;
    add8(acc, Hv[(size_t)g * 16 + f8]);   // self term
    int e = beg;
    for (; e + 4 <= end; e += 4) {        // 4-deep batch
        int s[4];
#pragma unroll
        for (int j = 0; j < 4; ++j) s[j] = src_csr[e + j];
        float4 r[4];
#pragma unroll
        for (int j = 0; j < 4; ++j) r[j] = Hv[(size_t)s[j] * 16 + f8];
#pragma unroll
        for (int j = 0; j < 4; ++j) add8(acc, r[j]);
    }
    for (; e < end; ++e) add8(acc, Hv[(size_t)src_csr[e] * 16 + f8]);
}

// Weighted version: acc = sum dis[s]*Hv[s] + dg*Hv[g] (HWS1 stored unscaled).
__device__ __forceinline__ void gather_row16w(const float4* __restrict__ Hv,
                                              const int* __restrict__ row_ptr,
                                              const int* __restrict__ src_csr,
                                              const float* __restrict__ dis,
                                              int g, float dg, int f8,
                                              float acc[8]) {
    int beg = row_ptr[g], end = row_ptr[g + 1];
#pragma unroll
    for (int k = 0; k < 8; ++k) acc[k] = 0.f;
    add8w(acc, Hv[(size_t)g * 16 + f8], dg);   // self term
    int e = beg;
    for (; e + 4 <= end; e += 4) {
        int s[4];
#pragma unroll
        for (int j = 0; j < 4; ++j) s[j] = src_csr[e + j];
        float wv[4];
#pragma unroll
        for (int j = 0; j < 4; ++j) wv[j] = dis[s[j]];
        float4 r[4];
#pragma unroll
        for (int j = 0; j < 4; ++j) r[j] = Hv[(size_t)s[j] * 16 + f8];
#pragma unroll
        for (int j = 0; j < 4; ++j) add8w(acc, r[j], wv[j]);
    }
    for (; e < end; ++e) {
        int s = src_csr[e];
        add8w(acc, Hv[(size_t)s * 16 + f8], dis[s]);
    }
}

// FUSED layer-1 gather + layer-2 GEMM, 512 threads.
__global__ __launch_bounds__(512) void k_gather_gemm(const __half* __restrict__ HWS1,
                                                     const int* __restrict__ row_ptr,
                                                     const int* __restrict__ src_csr,
                                                     const float* __restrict__ dis,
                                                     const float* __restrict__ bias,
                                                     const __half* __restrict__ Wt,
                                                     __half* __restrict__ HWS2,
                                                     int nN) {
    __shared__ __half xs[64 * 136];
    __shared__ int q;
    const int t = threadIdx.x;
    const int row0 = blockIdx.x * 64;
    const int l = t & 63;
    const int f8 = t & 15;            // lane within quarter-wave
    const int qbase = l & 48;         // base lane of this quarter in the wave
    const float4* Hv = (const float4*)HWS1;

    float bv[8];
    *(float4*)&bv[0] = ((const float4*)bias)[f8 * 2];
    *(float4*)&bv[4] = ((const float4*)bias)[f8 * 2 + 1];

    if (t == 0) q = 0;
    __syncthreads();

    for (;;) {
        int lr = 0;
        if (f8 == 0) lr = atomicAdd(&q, 1);
        lr = __shfl(lr, qbase, 64);
        if (lr >= 64) break;
        int g = row0 + lr;
        float acc[8];
        __half2 h[4];
        if (g < nN) {
            float dn = dis[g];
            gather_row16w(Hv, row_ptr, src_csr, dis, g, dn, f8, acc);
#pragma unroll
            for (int k = 0; k < 4; ++k)
                h[k] = __float22half2_rn(make_float2(
                    fmaxf(acc[2 * k] * dn + bv[2 * k], 0.f),
                    fmaxf(acc[2 * k + 1] * dn + bv[2 * k + 1], 0.f)));
        } else {
#pragma unroll
            for (int k = 0; k < 4; ++k) h[k] = __float2half2_rn(0.f);
        }
        *(float4*)&xs[lr * 136 + f8 * 8] = *(float4*)h;   // 16B ds_write_b128
    }
    __syncthreads();

    const int w = t >> 6;        // wave 0..7
    const int mrow = l & 15;
    const int kq = l >> 4;
    const int rgrp = (w & 3) * 16;   // row group
    const int cgrp = (w >> 2) * 4;   // col-tile group (4 tiles of 16)

    v8h a[4];
#pragma unroll
    for (int kk = 0; kk < 4; ++kk)
        a[kk] = *(const v8h*)&xs[(rgrp + mrow) * 136 + kk * 32 + kq * 8];

    v4f acc[4];
#pragma unroll
    for (int c = 0; c < 4; ++c) acc[c] = (v4f){0.f, 0.f, 0.f, 0.f};

#pragma unroll
    for (int kk = 0; kk < 4; ++kk) {
#pragma unroll
        for (int c = 0; c < 4; ++c) {
            v8h b = *(const v8h*)&Wt[(size_t)((cgrp + c) * 16 + mrow) * 128 + kk * 32 + kq * 8];
            acc[c] = __builtin_amdgcn_mfma_f32_16x16x32_f16(a[kk], b, acc[c], 0, 0, 0);
        }
    }

    float dn4[4];
#pragma unroll
    for (int r = 0; r < 4; ++r) {
        int grow = row0 + rgrp + kq * 4 + r;
        dn4[r] = (grow < nN) ? dis[grow] : 0.f;
    }
#pragma unroll
    for (int c = 0; c < 4; ++c) {
#pragma unroll
        for (int r = 0; r < 4; ++r) {
            int grow = row0 + rgrp + kq * 4 + r;
            if (grow < nN)
                HWS2[(size_t)grow * 128 + (cgrp + c) * 16 + mrow] =
                    __float2half(acc[c][r] * dn4[r]);
        }
    }
}

// FUSED layer-2 gather + layer-3 gemv (HWS2 is dis-prefolded at write):
//   hw3s[g] = dis[g] * dot(relu(dis[g]*S HWS2 + b2), W3)
__global__ __launch_bounds__(256) void k_gather_gemv(const __half* __restrict__ HWS2,
                                                     const int* __restrict__ row_ptr,
                                                     const int* __restrict__ src_csr,
                                                     const float* __restrict__ dis,
                                                     const float* __restrict__ bias,
                                                     const float* __restrict__ W3,
                                                     float* __restrict__ hw3s, int nN) {
    int g = blockIdx.x * 16 + (threadIdx.x >> 4);
    if (g >= nN) return;
    int f8 = threadIdx.x & 15;
    float acc[8];
    gather_row16((const float4*)HWS2, row_ptr, src_csr, g, f8, acc);
    float dn = dis[g];
    float bv[8], w3[8];
    *(float4*)&bv[0] = ((const float4*)bias)[f8 * 2];
    *(float4*)&bv[4] = ((const float4*)bias)[f8 * 2 + 1];
    *(float4*)&w3[0] = ((const float4*)W3)[f8 * 2];
    *(float4*)&w3[4] = ((const float4*)W3)[f8 * 2 + 1];
    float sum = 0.f;
#pragma unroll
    for (int k = 0; k < 8; ++k)
        sum += fmaxf(acc[k] * dn + bv[k], 0.f) * w3[k];
#pragma unroll
    for (int off = 8; off > 0; off >>= 1) sum += __shfl_down(sum, off, 16);
    if (f8 == 0) hw3s[g] = sum * dn;
}

// scalar pull-aggregation + final relu -> d_out
__global__ __launch_bounds__(256) void k_gather3(const float* __restrict__ hw3s,
                                                 const int* __restrict__ row_ptr,
                                                 const int* __restrict__ src_csr,
                                                 const float* __restrict__ dis,
                                                 const float* __restrict__ b3,
                                                 float* __restrict__ out, int nN) {
    int i = blockIdx.x * 256 + threadIdx.x;
    if (i >= nN) return;
    float acc = hw3s[i];
    int beg = row_ptr[i], end = row_ptr[i + 1];
    for (int e = beg; e < end; ++e) acc += hw3s[src_csr[e]];
    out[i] = fmaxf(acc * dis[i] + b3[0], 0.f);
}

extern "C" void kernel_launch(void* const* d_in, const int* in_sizes, int n_in,
                              void* d_out, int out_size, void* d_ws, size_t ws_size,
                              hipStream_t stream) {
    const float* x  = (const float*)d_in[0];
    const int*   ei = (const int*)d_in[1];
    const float* W1 = (const float*)d_in[2];
    const float* b1 = (const float*)d_in[3];
    const float* W2 = (const float*)d_in[4];
    const float* b2 = (const float*)d_in[5];
    const float* W3 = (const float*)d_in[6];
    const float* b3 = (const float*)d_in[7];

    const int nN = in_sizes[0] / 128;
    const int nE = in_sizes[1] / 2;
    const int* src = ei;
    const int* dst = ei + nE;

    const int nB = (nN + 255) / 256;   // scan blocks (<=256)

    // workspace layout
    char* p = (char*)d_ws;
    int*    cnt8     = (int*)p;           p += (size_t)nN * 8 * 4;
    int*    base8    = (int*)p;           p += (size_t)nN * 8 * 4;
    int*    excl     = (int*)p;           p += (size_t)nN * 4;
    int*    blk_sum  = (int*)p;           p += (size_t)(nB + 1) * 4;
    int*    row_ptr  = (int*)p;           p += (size_t)(nN + 1) * 4;
    int*    rank     = (int*)p;           p += (size_t)nE * 4;
    int*    src_csr  = (int*)p;           p += (size_t)nE * 4;
    float*  dis      = (float*)p;         p += (size_t)nN * 4;
    float*  hw3s     = (float*)p;         p += (size_t)nN * 4;
    p = (char*)(((uintptr_t)p + 255) & ~(uintptr_t)255);
    __half* Wt1      = (__half*)p;        p += (size_t)128 * 128 * 2;
    __half* Wt2      = (__half*)p;        p += (size_t)128 * 128 * 2;
    __half* bufA     = (__half*)p;        p += (size_t)nN * 128 * 2;  // HWS1
    p = (char*)(((uintptr_t)p + 255) & ~(uintptr_t)255);
    __half* bufB     = (__half*)p;        p += (size_t)nN * 128 * 2;  // HWS2

    const int BE  = (nE + 255) / 256;            // 2344
    const int BN  = (nN + 255) / 256;            // 196
    const int BG  = (nN + 63) / 64;              // 782
    const int BGV = (nN + 15) / 16;              // 3125
    const int BZ8 = (nN * 8 + 255) / 256;        // 1563 (cnt8 zero)

    // --- cnt8 zero + weight cast ---
    k_zero_wcast<<<BZ8 + 64, 256, 0, stream>>>(cnt8, nN * 8, BZ8, W1, W2, Wt1, Wt2);

    // --- 8-bank edge count/rank OVERLAPPED with layer-1 GEMM (dis-free) ---
    k_count_gemm<<<BE + BG, 256, 0, stream>>>(dst, cnt8, rank, nE, BE, nN,
                                              x, Wt1, bufA, nN);

    // --- CSR scan + norms + per-bank bases ---
    k_scan_blk<<<nB, 256, 0, stream>>>(cnt8, dis, excl, blk_sum, nN);
    k_scan_add<<<nB, 256, 0, stream>>>(excl, blk_sum, cnt8, row_ptr, base8, nN, nB);

    // --- atomic-free binning ---
    k_bin<<<BE, 256, 0, stream>>>(src, dst, rank, base8, src_csr, nE);

    // --- fused layer-1 gather (dis[s] FMA-folded) + layer-2 GEMM ---
    k_gather_gemm<<<BG, 512, 0, stream>>>(bufA, row_ptr, src_csr, dis, b1, Wt2,
                                          bufB, nN);

    // --- fused layer-2 gather + layer-3 gemv ---
    k_gather_gemv<<<BGV, 256, 0, stream>>>(bufB, row_ptr, src_csr, dis, b2, W3,
                                           hw3s, nN);

    // --- layer-3 scalar gather -> d_out ---
    k_gather3<<<BN, 256, 0, stream>>>(hw3s, row_ptr, src_csr, dis, b3,
                                      (float*)d_out, nN);
}

// Round 3
// 217.639 us; speedup vs baseline: 1.0398x; 1.0226x over previous
//
#include <hip/hip_runtime.h>
#include <hip/hip_fp16.h>

// ---------------------------------------------------------------------------
// 3-layer GCN, CSR-gather, fp16 dataflow + MFMA GEMM, fused pipeline R20:
//   zero+wcast:   cnt8=0  ||  Wt1/Wt2 cast
//   count:        8-BANK cnt histogram (bank=blockIdx&7; kills cross-XCD 64B
//                 line ping-pong of device atomics — verified R19) + rank
//   scan x2:      row_ptr (deg = sum of 8 banks) + dis + per-bank base8
//   gemm1+bin:    HWS1 = half(dis*(x@W1)) [dis folded in epilogue]
//                 || atomic-free CSR binning via base8+rank
//   gather+gemm2: h1 = relu(dis*S HWS1 + b1) -> LDS -> HWS2 = half(dis*(h1@W2))
//                 [DEPTH-8 gather: 8 rows in flight per quarter-wave + masked
//                  depth-8 tail — gather is LATENCY-bound (R19 counters:
//                  1 VMEM/69cy/CU, 40% occ), so double the MLP]
//   gather+gemv:  hw3s = dis * dot(relu(dis*S HWS2 + b2), W3)   [depth-8]
//   gather3:      out = relu(dis*S hw3s + b3)
// Lessons: R4/R5 never force min-waves. R7/R8/R16: gather is scattered-
// REQUEST/latency bound. R13: VGPR<64 hot kernels. R14/R15: rank trick.
// R17: quarter-wave gather. R18 FAILED: row sort no locality; scale pass =
// critical-path cost. R19: banked count WORKS; weighted gather (dis[s] load
// per edge) FAILED (+50% scattered requests on latency-bound kernel).
// ---------------------------------------------------------------------------

typedef _Float16 v8h __attribute__((ext_vector_type(8)));
typedef float v4f __attribute__((ext_vector_type(4)));

// fused: zero cnt8 (blocks [0,BZ)) + weight cast (blocks >= BZ)
__global__ __launch_bounds__(256) void k_zero_wcast(int* __restrict__ cnt8, int n8,
                                                    int BZ,
                                                    const float* __restrict__ W1,
                                                    const float* __restrict__ W2,
                                                    __half* __restrict__ Wt1,
                                                    __half* __restrict__ Wt2) {
    int b = blockIdx.x;
    if (b < BZ) {
        int i = b * 256 + threadIdx.x;
        if (i < n8) cnt8[i] = 0;
    } else {
        int i = (b - BZ) * 256 + threadIdx.x;   // 0..16383
        int k = i >> 7, c = i & 127;
        Wt1[c * 128 + k] = __float2half(W1[i]);
        Wt2[c * 128 + k] = __float2half(W2[i]);
    }
}

// 8-bank edge count + rank record. bank = blockIdx&7: consecutive blocks
// round-robin XCDs, so each bank's counters stay XCD-local (R19 verified).
__global__ __launch_bounds__(256) void k_count(const int* __restrict__ dst,
                                               int* __restrict__ cnt8,
                                               int* __restrict__ rank,
                                               int nE, int nN) {
    int e = blockIdx.x * 256 + threadIdx.x;
    if (e < nE) {
        int bank = blockIdx.x & 7;
        rank[e] = atomicAdd(&cnt8[bank * nN + dst[e]], 1);
    }
}

// scan stage 1: deg = sum of 8 banks, fused dis = rsqrt(deg+1)
__global__ __launch_bounds__(256) void k_scan_blk(const int* __restrict__ cnt8,
                                                  float* __restrict__ dis,
                                                  int* __restrict__ excl,
                                                  int* __restrict__ blk_sum, int nN) {
    __shared__ int sm[256];
    const int t = threadIdx.x;
    int i = blockIdx.x * 256 + t;
    int v = 0;
    if (i < nN) {
#pragma unroll
        for (int b = 0; b < 8; ++b) v += cnt8[b * nN + i];
        dis[i] = rsqrtf((float)v + 1.0f);
    }
    sm[t] = v;
    __syncthreads();
#pragma unroll
    for (int off = 1; off < 256; off <<= 1) {
        int x = (t >= off) ? sm[t - off] : 0;
        __syncthreads();
        sm[t] += x;
        __syncthreads();
    }
    if (i < nN) excl[i] = sm[t] - v;
    if (t == 255) blk_sum[blockIdx.x] = sm[255];
}

// stage 2+3 fused + per-bank base emission:
// base8[i*8+b] = row_ptr[i] + sum_{b'<b} cnt8[b'][i]
__global__ __launch_bounds__(256) void k_scan_add(const int* __restrict__ excl,
                                                  const int* __restrict__ blk_sum,
                                                  const int* __restrict__ cnt8,
                                                  int* __restrict__ row_ptr,
                                                  int* __restrict__ base8,
                                                  int nN, int nB) {
    __shared__ int sm[256];
    const int t = threadIdx.x;
    int v = (t < nB) ? blk_sum[t] : 0;
    sm[t] = v;
    __syncthreads();
#pragma unroll
    for (int off = 1; off < 256; off <<= 1) {
        int x = (t >= off) ? sm[t - off] : 0;
        __syncthreads();
        sm[t] += x;
        __syncthreads();
    }
    int i = blockIdx.x * 256 + t;
    if (i < nN) {
        int b = i >> 8;
        int rp = excl[i] + sm[b] - blk_sum[b];
        row_ptr[i] = rp;
        int off = rp;
#pragma unroll
        for (int bk = 0; bk < 8; ++bk) {
            base8[i * 8 + bk] = off;
            off += cnt8[bk * nN + i];
        }
    }
    if (i == 0) row_ptr[nN] = sm[255];
}

// FUSED dispatch: blocks [0,BG) = layer-1 MFMA GEMM with dis epilogue;
// blocks >= BG = atomic-free CSR binning (bank recomputed = (blockIdx-BG)&7,
// identical e->bank mapping as k_count).
__global__ __launch_bounds__(256) void k_gemm_bin(const float* __restrict__ X32,
                                                  const __half* __restrict__ Wt,
                                                  const float* __restrict__ dis,
                                                  __half* __restrict__ HWS,
                                                  int nrows, int BG,
                                                  const int* __restrict__ src,
                                                  const int* __restrict__ dst,
                                                  const int* __restrict__ rank,
                                                  const int* __restrict__ base8,
                                                  int* __restrict__ src_csr, int nE) {
    __shared__ __half xs[64 * 136];
    if (blockIdx.x >= BG) {
        // --- binning path (no atomics) ---
        int eb = blockIdx.x - BG;
        int e = eb * 256 + threadIdx.x;
        if (e < nE) {
            int d = dst[e];
            int bank = eb & 7;
            src_csr[base8[d * 8 + bank] + rank[e]] = src[e];
        }
        return;
    }

    // --- GEMM path: HWS = half(dis * (x @ W1)) ---
    const int t = threadIdx.x;
    const int row0 = blockIdx.x * 64;

#pragma unroll
    for (int i = 0; i < 8; ++i) {
        int f = t + i * 256;
        int r = f >> 5, k4 = f & 31;
        int gr = row0 + r;
        float4 v = make_float4(0.f, 0.f, 0.f, 0.f);
        if (gr < nrows) v = ((const float4*)X32)[(size_t)gr * 32 + k4];
        __half2 h01 = __float22half2_rn(make_float2(v.x, v.y));
        __half2 h23 = __float22half2_rn(make_float2(v.z, v.w));
        float2 packed;
        *(__half2*)&packed.x = h01;
        *(__half2*)&packed.y = h23;
        *(float2*)&xs[r * 136 + k4 * 4] = packed;
    }
    __syncthreads();

    const int w = t >> 6;
    const int l = t & 63;
    const int mrow = l & 15;
    const int kq = l >> 4;

    v8h a[4];
#pragma unroll
    for (int kk = 0; kk < 4; ++kk)
        a[kk] = *(const v8h*)&xs[(w * 16 + mrow) * 136 + kk * 32 + kq * 8];

    v4f acc[8];
#pragma unroll
    for (int c = 0; c < 8; ++c) acc[c] = (v4f){0.f, 0.f, 0.f, 0.f};

#pragma unroll
    for (int kk = 0; kk < 4; ++kk) {
#pragma unroll
        for (int c = 0; c < 8; ++c) {
            v8h b = *(const v8h*)&Wt[(size_t)(c * 16 + mrow) * 128 + kk * 32 + kq * 8];
            acc[c] = __builtin_amdgcn_mfma_f32_16x16x32_f16(a[kk], b, acc[c], 0, 0, 0);
        }
    }

    float dn[4];
#pragma unroll
    for (int r = 0; r < 4; ++r) {
        int grow = row0 + w * 16 + kq * 4 + r;
        dn[r] = (grow < nrows) ? dis[grow] : 0.f;
    }
#pragma unroll
    for (int c = 0; c < 8; ++c) {
#pragma unroll
        for (int r = 0; r < 4; ++r) {
            int grow = row0 + w * 16 + kq * 4 + r;
            if (grow < nrows)
                HWS[(size_t)grow * 128 + c * 16 + mrow] =
                    __float2half(acc[c][r] * dn[r]);
        }
    }
}

// add 8 halves (packed in a float4) into acc[8] (fp32)
__device__ __forceinline__ void add8(float acc[8], float4 r) {
    __half2* hp = (__half2*)&r;
#pragma unroll
    for (int k = 0; k < 4; ++k) {
        float2 f = __half22float2(hp[k]);
        acc[2 * k] += f.x;
        acc[2 * k + 1] += f.y;
    }
}

// QUARTER-WAVE gather, DEPTH-8: 16 lanes per node row, 16B per lane; 8 row
// loads in flight per batch + one masked depth-8 tail (clamped index loads,
// predicated accumulate) -> ~2x MLP vs depth-4, no serial scalar cleanup.
__device__ __forceinline__ void gather_row16(const float4* __restrict__ Hv,
                                             const int* __restrict__ row_ptr,
                                             const int* __restrict__ src_csr,
                                             int g, int f8, float acc[8]) {
    int beg = row_ptr[g], end = row_ptr[g + 1];
#pragma unroll
    for (int k = 0; k < 8; ++k) acc[k] = 0.f;
    add8(acc, Hv[(size_t)g * 16 + f8]);   // self term
    int e = beg;
    for (; e + 8 <= end; e += 8) {
        int s[8];
#pragma unroll
        for (int j = 0; j < 8; ++j) s[j] = src_csr[e + j];
        float4 r[8];
#pragma unroll
        for (int j = 0; j < 8; ++j) r[j] = Hv[(size_t)s[j] * 16 + f8];
#pragma unroll
        for (int j = 0; j < 8; ++j) add8(acc, r[j]);
    }
    int rem = end - e;
    if (rem > 0) {
        int last = end - 1;
        int s[8];
#pragma unroll
        for (int j = 0; j < 8; ++j) s[j] = src_csr[(e + j <= last) ? e + j : last];
        float4 r[8];
#pragma unroll
        for (int j = 0; j < 8; ++j) r[j] = Hv[(size_t)s[j] * 16 + f8];
#pragma unroll
        for (int j = 0; j < 8; ++j)
            if (j < rem) add8(acc, r[j]);
    }
}

// FUSED layer-1 gather + layer-2 GEMM, 512 threads.
__global__ __launch_bounds__(512) void k_gather_gemm(const __half* __restrict__ HWS1,
                                                     const int* __restrict__ row_ptr,
                                                     const int* __restrict__ src_csr,
                                                     const float* __restrict__ dis,
                                                     const float* __restrict__ bias,
                                                     const __half* __restrict__ Wt,
                                                     __half* __restrict__ HWS2,
                                                     int nN) {
    __shared__ __half xs[64 * 136];
    __shared__ int q;
    const int t = threadIdx.x;
    const int row0 = blockIdx.x * 64;
    const int l = t & 63;
    const int f8 = t & 15;            // lane within quarter-wave
    const int qbase = l & 48;         // base lane of this quarter in the wave
    const float4* Hv = (const float4*)HWS1;

    float bv[8];
    *(float4*)&bv[0] = ((const float4*)bias)[f8 * 2];
    *(float4*)&bv[4] = ((const float4*)bias)[f8 * 2 + 1];

    if (t == 0) q = 0;
    __syncthreads();

    for (;;) {
        int lr = 0;
        if (f8 == 0) lr = atomicAdd(&q, 1);
        lr = __shfl(lr, qbase, 64);
        if (lr >= 64) break;
        int g = row0 + lr;
        float acc[8];
        __half2 h[4];
        if (g < nN) {
            gather_row16(Hv, row_ptr, src_csr, g, f8, acc);
            float dn = dis[g];
#pragma unroll
            for (int k = 0; k < 4; ++k)
                h[k] = __float22half2_rn(make_float2(
                    fmaxf(acc[2 * k] * dn + bv[2 * k], 0.f),
                    fmaxf(acc[2 * k + 1] * dn + bv[2 * k + 1], 0.f)));
        } else {
#pragma unroll
            for (int k = 0; k < 4; ++k) h[k] = __float2half2_rn(0.f);
        }
        *(float4*)&xs[lr * 136 + f8 * 8] = *(float4*)h;   // 16B ds_write_b128
    }
    __syncthreads();

    const int w = t >> 6;        // wave 0..7
    const int mrow = l & 15;
    const int kq = l >> 4;
    const int rgrp = (w & 3) * 16;   // row group
    const int cgrp = (w >> 2) * 4;   // col-tile group (4 tiles of 16)

    v8h a[4];
#pragma unroll
    for (int kk = 0; kk < 4; ++kk)
        a[kk] = *(const v8h*)&xs[(rgrp + mrow) * 136 + kk * 32 + kq * 8];

    v4f acc[4];
#pragma unroll
    for (int c = 0; c < 4; ++c) acc[c] = (v4f){0.f, 0.f, 0.f, 0.f};

#pragma unroll
    for (int kk = 0; kk < 4; ++kk) {
#pragma unroll
        for (int c = 0; c < 4; ++c) {
            v8h b = *(const v8h*)&Wt[(size_t)((cgrp + c) * 16 + mrow) * 128 + kk * 32 + kq * 8];
            acc[c] = __builtin_amdgcn_mfma_f32_16x16x32_f16(a[kk], b, acc[c], 0, 0, 0);
        }
    }

    float dn4[4];
#pragma unroll
    for (int r = 0; r < 4; ++r) {
        int grow = row0 + rgrp + kq * 4 + r;
        dn4[r] = (grow < nN) ? dis[grow] : 0.f;
    }
#pragma unroll
    for (int c = 0; c < 4; ++c) {
#pragma unroll
        for (int r = 0; r < 4; ++r) {
            int grow = row0 + rgrp + kq * 4 + r;
            if (grow < nN)
                HWS2[(size_t)grow * 128 + (cgrp + c) * 16 + mrow] =
                    __float2half(acc[c][r] * dn4[r]);
        }
    }
}

// FUSED layer-2 gather + layer-3 gemv (quarter-wave depth-8 gather):
//   hw3s[g] = dis[g] * dot(relu(dis[g]*S HWS2 + b2), W3)
__global__ __launch_bounds__(256) void k_gather_gemv(const __half* __restrict__ HWS2,
                                                     const int* __restrict__ row_ptr,
                                                     const int* __restrict__ src_csr,
                                                     const float* __restrict__ dis,
                                                     const float* __restrict__ bias,
                                                     const float* __restrict__ W3,
                                                     float* __restrict__ hw3s, int nN) {
    int g = blockIdx.x * 16 + (threadIdx.x >> 4);
    if (g >= nN) return;
    int f8 = threadIdx.x & 15;
    float acc[8];
    gather_row16((const float4*)HWS2, row_ptr, src_csr, g, f8, acc);
    float dn = dis[g];
    float bv[8], w3[8];
    *(float4*)&bv[0] = ((const float4*)bias)[f8 * 2];
    *(float4*)&bv[4] = ((const float4*)bias)[f8 * 2 + 1];
    *(float4*)&w3[0] = ((const float4*)W3)[f8 * 2];
    *(float4*)&w3[4] = ((const float4*)W3)[f8 * 2 + 1];
    float sum = 0.f;
#pragma unroll
    for (int k = 0; k < 8; ++k)
        sum += fmaxf(acc[k] * dn + bv[k], 0.f) * w3[k];
#pragma unroll
    for (int off = 8; off > 0; off >>= 1) sum += __shfl_down(sum, off, 16);
    if (f8 == 0) hw3s[g] = sum * dn;
}

// scalar pull-aggregation + final relu -> d_out
__global__ __launch_bounds__(256) void k_gather3(const float* __restrict__ hw3s,
                                                 const int* __restrict__ row_ptr,
                                                 const int* __restrict__ src_csr,
                                                 const float* __restrict__ dis,
                                                 const float* __restrict__ b3,
                                                 float* __restrict__ out, int nN) {
    int i = blockIdx.x * 256 + threadIdx.x;
    if (i >= nN) return;
    float acc = hw3s[i];
    int beg = row_ptr[i], end = row_ptr[i + 1];
    for (int e = beg; e < end; ++e) acc += hw3s[src_csr[e]];
    out[i] = fmaxf(acc * dis[i] + b3[0], 0.f);
}

extern "C" void kernel_launch(void* const* d_in, const int* in_sizes, int n_in,
                              void* d_out, int out_size, void* d_ws, size_t ws_size,
                              hipStream_t stream) {
    const float* x  = (const float*)d_in[0];
    const int*   ei = (const int*)d_in[1];
    const float* W1 = (const float*)d_in[2];
    const float* b1 = (const float*)d_in[3];
    const float* W2 = (const float*)d_in[4];
    const float* b2 = (const float*)d_in[5];
    const float* W3 = (const float*)d_in[6];
    const float* b3 = (const float*)d_in[7];

    const int nN = in_sizes[0] / 128;
    const int nE = in_sizes[1] / 2;
    const int* src = ei;
    const int* dst = ei + nE;

    const int nB = (nN + 255) / 256;   // scan blocks (<=256)

    // workspace layout
    char* p = (char*)d_ws;
    int*    cnt8     = (int*)p;           p += (size_t)nN * 8 * 4;
    int*    base8    = (int*)p;           p += (size_t)nN * 8 * 4;
    int*    excl     = (int*)p;           p += (size_t)nN * 4;
    int*    blk_sum  = (int*)p;           p += (size_t)(nB + 1) * 4;
    int*    row_ptr  = (int*)p;           p += (size_t)(nN + 1) * 4;
    int*    rank     = (int*)p;           p += (size_t)nE * 4;
    int*    src_csr  = (int*)p;           p += (size_t)nE * 4;
    float*  dis      = (float*)p;         p += (size_t)nN * 4;
    float*  hw3s     = (float*)p;         p += (size_t)nN * 4;
    p = (char*)(((uintptr_t)p + 255) & ~(uintptr_t)255);
    __half* Wt1      = (__half*)p;        p += (size_t)128 * 128 * 2;
    __half* Wt2      = (__half*)p;        p += (size_t)128 * 128 * 2;
    __half* bufA     = (__half*)p;        p += (size_t)nN * 128 * 2;  // HWS1
    p = (char*)(((uintptr_t)p + 255) & ~(uintptr_t)255);
    __half* bufB     = (__half*)p;        p += (size_t)nN * 128 * 2;  // HWS2

    const int BE  = (nE + 255) / 256;            // 2344
    const int BN  = (nN + 255) / 256;            // 196
    const int BG  = (nN + 63) / 64;              // 782
    const int BGV = (nN + 15) / 16;              // 3125
    const int BZ8 = (nN * 8 + 255) / 256;        // 1563 (cnt8 zero)

    // --- cnt8 zero + weight cast ---
    k_zero_wcast<<<BZ8 + 64, 256, 0, stream>>>(cnt8, nN * 8, BZ8, W1, W2, Wt1, Wt2);

    // --- 8-bank edge count/rank (XCD-local atomics) ---
    k_count<<<BE, 256, 0, stream>>>(dst, cnt8, rank, nE, nN);

    // --- CSR scan + norms + per-bank bases ---
    k_scan_blk<<<nB, 256, 0, stream>>>(cnt8, dis, excl, blk_sum, nN);
    k_scan_add<<<nB, 256, 0, stream>>>(excl, blk_sum, cnt8, row_ptr, base8, nN, nB);

    // --- layer-1 GEMM (dis epilogue) OVERLAPPED with atomic-free binning ---
    k_gemm_bin<<<BG + BE, 256, 0, stream>>>(x, Wt1, dis, bufA, nN, BG,
                                            src, dst, rank, base8, src_csr, nE);

    // --- fused layer-1 gather + layer-2 GEMM: HWS1 -> HWS2 (512 thr) ---
    k_gather_gemm<<<BG, 512, 0, stream>>>(bufA, row_ptr, src_csr, dis, b1, Wt2,
                                          bufB, nN);

    // --- fused layer-2 gather + layer-3 gemv: HWS2 -> hw3s ---
    k_gather_gemv<<<BGV, 256, 0, stream>>>(bufB, row_ptr, src_csr, dis, b2, W3,
                                           hw3s, nN);

    // --- layer-3 scalar gather -> d_out ---
    k_gather3<<<BN, 256, 0, stream>>>(hw3s, row_ptr, src_csr, dis, b3,
                                      (float*)d_out, nN);
}

// Round 4
// 211.622 us; speedup vs baseline: 1.0694x; 1.0284x over previous
//
#include <hip/hip_runtime.h>
#include <hip/hip_fp16.h>

// ---------------------------------------------------------------------------
// 3-layer GCN, CSR-gather, fp16 dataflow + MFMA GEMM, fused pipeline R21:
// EXACT R17 (211.9us) structure + ONE change: 8-banked count histogram.
//   memset:       cnt8 = 0
//   count+wcast:  8-BANK cnt histogram (bank=blockIdx&7 ~ XCD-local; kills
//                 cross-XCD 64B atomic line ping-pong, verified R19) || Wt cast
//   scan x2:      row_ptr (deg = sum of banks) + dis + per-bank base8
//   gemm1+bin:    HWS1 = half(dis*(x@W1)) || CSR bin: base8[d*8+bank]+rank
//   gather+gemm2: h1 = relu(dis*S HWS1 + b1) -> LDS -> HWS2 = half(dis*(h1@W2))
//                 [QUARTER-WAVE depth-4 gather: VGPR 36, occ ~40% — R20 proved
//                  depth-8 trades occupancy 1:1 for MLP, no net gain]
//   gather+gemv:  hw3s = dis * dot(relu(dis*S HWS2 + b2), W3)
//   gather3:      out = relu(dis*S hw3s + b3)
// Lessons: R4/R5 never force min-waves. R7/R8/R16: gather is scattered-
// REQUEST/latency bound. R13: VGPR<64 hot kernels. R14/R15: rank trick.
// R17: quarter-wave gather. R18 FAILED: row sort (no locality), scale pass.
// R19: banked count WORKS; per-edge dis[s] loads FAILED. R20: depth-8 FAILED
// (occupancy 40->30 cancels 2x MLP).
// ---------------------------------------------------------------------------

typedef _Float16 v8h __attribute__((ext_vector_type(8)));
typedef float v4f __attribute__((ext_vector_type(4)));

// fused: 8-bank edge count + rank record (blocks [0,BE)) + weight cast.
// bank = blockIdx&7: consecutive blocks round-robin XCDs -> each bank's
// counter lines stay in one XCD's L2.
__global__ __launch_bounds__(256) void k_count_wcast(const int* __restrict__ dst,
                                                     int* __restrict__ cnt8,
                                                     int* __restrict__ rank, int nE,
                                                     int BE, int nN,
                                                     const float* __restrict__ W1,
                                                     const float* __restrict__ W2,
                                                     __half* __restrict__ Wt1,
                                                     __half* __restrict__ Wt2) {
    int b = blockIdx.x;
    if (b < BE) {
        int e = b * 256 + threadIdx.x;
        if (e < nE) {
            int bank = b & 7;
            rank[e] = atomicAdd(&cnt8[bank * nN + dst[e]], 1);
        }
    } else {
        int i = (b - BE) * 256 + threadIdx.x;   // 0..16383
        int k = i >> 7, c = i & 127;
        Wt1[c * 128 + k] = __float2half(W1[i]);
        Wt2[c * 128 + k] = __float2half(W2[i]);
    }
}

// scan stage 1: deg = sum of 8 banks, fused dis = rsqrt(deg+1)
__global__ __launch_bounds__(256) void k_scan_blk(const int* __restrict__ cnt8,
                                                  float* __restrict__ dis,
                                                  int* __restrict__ excl,
                                                  int* __restrict__ blk_sum, int nN) {
    __shared__ int sm[256];
    const int t = threadIdx.x;
    int i = blockIdx.x * 256 + t;
    int v = 0;
    if (i < nN) {
#pragma unroll
        for (int b = 0; b < 8; ++b) v += cnt8[b * nN + i];
        dis[i] = rsqrtf((float)v + 1.0f);
    }
    sm[t] = v;
    __syncthreads();
#pragma unroll
    for (int off = 1; off < 256; off <<= 1) {
        int x = (t >= off) ? sm[t - off] : 0;
        __syncthreads();
        sm[t] += x;
        __syncthreads();
    }
    if (i < nN) excl[i] = sm[t] - v;
    if (t == 255) blk_sum[blockIdx.x] = sm[255];
}

// stage 2+3 fused + per-bank base emission:
// base8[i*8+b] = row_ptr[i] + sum_{b'<b} cnt8[b'][i]
__global__ __launch_bounds__(256) void k_scan_add(const int* __restrict__ excl,
                                                  const int* __restrict__ blk_sum,
                                                  const int* __restrict__ cnt8,
                                                  int* __restrict__ row_ptr,
                                                  int* __restrict__ base8,
                                                  int nN, int nB) {
    __shared__ int sm[256];
    const int t = threadIdx.x;
    int v = (t < nB) ? blk_sum[t] : 0;
    sm[t] = v;
    __syncthreads();
#pragma unroll
    for (int off = 1; off < 256; off <<= 1) {
        int x = (t >= off) ? sm[t - off] : 0;
        __syncthreads();
        sm[t] += x;
        __syncthreads();
    }
    int i = blockIdx.x * 256 + t;
    if (i < nN) {
        int b = i >> 8;
        int rp = excl[i] + sm[b] - blk_sum[b];
        row_ptr[i] = rp;
        int off = rp;
#pragma unroll
        for (int bk = 0; bk < 8; ++bk) {
            base8[i * 8 + bk] = off;
            off += cnt8[bk * nN + i];
        }
    }
    if (i == 0) row_ptr[nN] = sm[255];
}

// add 8 halves (packed in a float4) into acc[8] (fp32)
__device__ __forceinline__ void add8(float acc[8], float4 r) {
    __half2* hp = (__half2*)&r;
#pragma unroll
    for (int k = 0; k < 4; ++k) {
        float2 f = __half22float2(hp[k]);
        acc[2 * k] += f.x;
        acc[2 * k + 1] += f.y;
    }
}

// QUARTER-WAVE gather: 16 lanes per node row, 16B (8 halves) per lane.
// One wave-load instruction covers 4 node rows (1KB). acc[8] fp32, incl self.
__device__ __forceinline__ void gather_row16(const float4* __restrict__ Hv,
                                             const int* __restrict__ row_ptr,
                                             const int* __restrict__ src_csr,
                                             int g, int f8, float acc[8]) {
    int beg = row_ptr[g], end = row_ptr[g + 1];
#pragma unroll
    for (int k = 0; k < 8; ++k) acc[k] = 0.f;
    add8(acc, Hv[(size_t)g * 16 + f8]);   // self term
    int e = beg;
    for (; e + 4 <= end; e += 4) {        // 4-deep batch: r[4]x4 = 16 VGPRs
        int s[4];
#pragma unroll
        for (int j = 0; j < 4; ++j) s[j] = src_csr[e + j];
        float4 r[4];
#pragma unroll
        for (int j = 0; j < 4; ++j) r[j] = Hv[(size_t)s[j] * 16 + f8];
#pragma unroll
        for (int j = 0; j < 4; ++j) add8(acc, r[j]);
    }
    for (; e < end; ++e) add8(acc, Hv[(size_t)src_csr[e] * 16 + f8]);
}

// FUSED dispatch: blocks [0,BG) = layer-1 MFMA GEMM; blocks >=BG = CSR bin.
// Bin path atomic-free: pos = base8[d*8+bank] + rank; bank=(blockIdx-BG)&7
// matches k_count_wcast's e->bank mapping (identical block geometry).
__global__ __launch_bounds__(256) void k_gemm_bin(const float* __restrict__ X32,
                                                  const __half* __restrict__ Wt,
                                                  const float* __restrict__ dis,
                                                  __half* __restrict__ HWS,
                                                  int nrows, int BG,
                                                  const int* __restrict__ src,
                                                  const int* __restrict__ dst,
                                                  const int* __restrict__ rank,
                                                  const int* __restrict__ base8,
                                                  int* __restrict__ src_csr, int nE) {
    __shared__ __half xs[64 * 136];
    if (blockIdx.x >= BG) {
        // --- binning path (no atomics) ---
        int eb = blockIdx.x - BG;
        int e = eb * 256 + threadIdx.x;
        if (e < nE) {
            int d = dst[e];
            int bank = eb & 7;
            src_csr[base8[d * 8 + bank] + rank[e]] = src[e];
        }
        return;
    }

    // --- GEMM path ---
    const int t = threadIdx.x;
    const int row0 = blockIdx.x * 64;

#pragma unroll
    for (int i = 0; i < 8; ++i) {
        int f = t + i * 256;
        int r = f >> 5, k4 = f & 31;
        int gr = row0 + r;
        float4 v = make_float4(0.f, 0.f, 0.f, 0.f);
        if (gr < nrows) v = ((const float4*)X32)[(size_t)gr * 32 + k4];
        __half2 h01 = __float22half2_rn(make_float2(v.x, v.y));
        __half2 h23 = __float22half2_rn(make_float2(v.z, v.w));
        float2 packed;
        *(__half2*)&packed.x = h01;
        *(__half2*)&packed.y = h23;
        *(float2*)&xs[r * 136 + k4 * 4] = packed;
    }
    __syncthreads();

    const int w = t >> 6;
    const int l = t & 63;
    const int mrow = l & 15;
    const int kq = l >> 4;

    v8h a[4];
#pragma unroll
    for (int kk = 0; kk < 4; ++kk)
        a[kk] = *(const v8h*)&xs[(w * 16 + mrow) * 136 + kk * 32 + kq * 8];

    v4f acc[8];
#pragma unroll
    for (int c = 0; c < 8; ++c) acc[c] = (v4f){0.f, 0.f, 0.f, 0.f};

#pragma unroll
    for (int kk = 0; kk < 4; ++kk) {
#pragma unroll
        for (int c = 0; c < 8; ++c) {
            v8h b = *(const v8h*)&Wt[(size_t)(c * 16 + mrow) * 128 + kk * 32 + kq * 8];
            acc[c] = __builtin_amdgcn_mfma_f32_16x16x32_f16(a[kk], b, acc[c], 0, 0, 0);
        }
    }

    float dn[4];
#pragma unroll
    for (int r = 0; r < 4; ++r) {
        int grow = row0 + w * 16 + kq * 4 + r;
        dn[r] = (grow < nrows) ? dis[grow] : 0.f;
    }
#pragma unroll
    for (int c = 0; c < 8; ++c) {
#pragma unroll
        for (int r = 0; r < 4; ++r) {
            int grow = row0 + w * 16 + kq * 4 + r;
            if (grow < nrows)
                HWS[(size_t)grow * 128 + c * 16 + mrow] =
                    __float2half(acc[c][r] * dn[r]);
        }
    }
}

// FUSED layer-1 gather + layer-2 GEMM, 512 threads.
//   phase 1: 32 quarter-waves pull node slots from an LDS queue; each gathers
//            a full 128-col row with 16 lanes x 16B (4 rows per wave-load).
//   phase 2: 8 MFMA waves; wave w: rows (w&3)*16..+16, col-tiles (w>>2)*4..+4
__global__ __launch_bounds__(512) void k_gather_gemm(const __half* __restrict__ HWS1,
                                                     const int* __restrict__ row_ptr,
                                                     const int* __restrict__ src_csr,
                                                     const float* __restrict__ dis,
                                                     const float* __restrict__ bias,
                                                     const __half* __restrict__ Wt,
                                                     __half* __restrict__ HWS2,
                                                     int nN) {
    __shared__ __half xs[64 * 136];
    __shared__ int q;
    const int t = threadIdx.x;
    const int row0 = blockIdx.x * 64;
    const int l = t & 63;
    const int f8 = t & 15;            // lane within quarter-wave
    const int qbase = l & 48;         // base lane of this quarter in the wave
    const float4* Hv = (const float4*)HWS1;

    float bv[8];
    *(float4*)&bv[0] = ((const float4*)bias)[f8 * 2];
    *(float4*)&bv[4] = ((const float4*)bias)[f8 * 2 + 1];

    if (t == 0) q = 0;
    __syncthreads();

    for (;;) {
        int lr = 0;
        if (f8 == 0) lr = atomicAdd(&q, 1);
        lr = __shfl(lr, qbase, 64);
        if (lr >= 64) break;
        int g = row0 + lr;
        float acc[8];
        __half2 h[4];
        if (g < nN) {
            gather_row16(Hv, row_ptr, src_csr, g, f8, acc);
            float dn = dis[g];
#pragma unroll
            for (int k = 0; k < 4; ++k)
                h[k] = __float22half2_rn(make_float2(
                    fmaxf(acc[2 * k] * dn + bv[2 * k], 0.f),
                    fmaxf(acc[2 * k + 1] * dn + bv[2 * k + 1], 0.f)));
        } else {
#pragma unroll
            for (int k = 0; k < 4; ++k) h[k] = __float2half2_rn(0.f);
        }
        *(float4*)&xs[lr * 136 + f8 * 8] = *(float4*)h;   // 16B ds_write_b128
    }
    __syncthreads();

    const int w = t >> 6;        // wave 0..7
    const int mrow = l & 15;
    const int kq = l >> 4;
    const int rgrp = (w & 3) * 16;   // row group
    const int cgrp = (w >> 2) * 4;   // col-tile group (4 tiles of 16)

    v8h a[4];
#pragma unroll
    for (int kk = 0; kk < 4; ++kk)
        a[kk] = *(const v8h*)&xs[(rgrp + mrow) * 136 + kk * 32 + kq * 8];

    v4f acc[4];
#pragma unroll
    for (int c = 0; c < 4; ++c) acc[c] = (v4f){0.f, 0.f, 0.f, 0.f};

#pragma unroll
    for (int kk = 0; kk < 4; ++kk) {
#pragma unroll
        for (int c = 0; c < 4; ++c) {
            v8h b = *(const v8h*)&Wt[(size_t)((cgrp + c) * 16 + mrow) * 128 + kk * 32 + kq * 8];
            acc[c] = __builtin_amdgcn_mfma_f32_16x16x32_f16(a[kk], b, acc[c], 0, 0, 0);
        }
    }

    float dn4[4];
#pragma unroll
    for (int r = 0; r < 4; ++r) {
        int grow = row0 + rgrp + kq * 4 + r;
        dn4[r] = (grow < nN) ? dis[grow] : 0.f;
    }
#pragma unroll
    for (int c = 0; c < 4; ++c) {
#pragma unroll
        for (int r = 0; r < 4; ++r) {
            int grow = row0 + rgrp + kq * 4 + r;
            if (grow < nN)
                HWS2[(size_t)grow * 128 + (cgrp + c) * 16 + mrow] =
                    __float2half(acc[c][r] * dn4[r]);
        }
    }
}

// FUSED layer-2 gather + layer-3 gemv (quarter-wave gather, 16 nodes/block):
//   hw3s[g] = dis[g] * dot(relu(dis[g]*S HWS2 + b2), W3)
__global__ __launch_bounds__(256) void k_gather_gemv(const __half* __restrict__ HWS2,
                                                     const int* __restrict__ row_ptr,
                                                     const int* __restrict__ src_csr,
                                                     const float* __restrict__ dis,
                                                     const float* __restrict__ bias,
                                                     const float* __restrict__ W3,
                                                     float* __restrict__ hw3s, int nN) {
    int g = blockIdx.x * 16 + (threadIdx.x >> 4);
    if (g >= nN) return;
    int f8 = threadIdx.x & 15;
    float acc[8];
    gather_row16((const float4*)HWS2, row_ptr, src_csr, g, f8, acc);
    float dn = dis[g];
    float bv[8], w3[8];
    *(float4*)&bv[0] = ((const float4*)bias)[f8 * 2];
    *(float4*)&bv[4] = ((const float4*)bias)[f8 * 2 + 1];
    *(float4*)&w3[0] = ((const float4*)W3)[f8 * 2];
    *(float4*)&w3[4] = ((const float4*)W3)[f8 * 2 + 1];
    float sum = 0.f;
#pragma unroll
    for (int k = 0; k < 8; ++k)
        sum += fmaxf(acc[k] * dn + bv[k], 0.f) * w3[k];
#pragma unroll
    for (int off = 8; off > 0; off >>= 1) sum += __shfl_down(sum, off, 16);
    if (f8 == 0) hw3s[g] = sum * dn;
}

// scalar pull-aggregation + final relu -> d_out
__global__ __launch_bounds__(256) void k_gather3(const float* __restrict__ hw3s,
                                                 const int* __restrict__ row_ptr,
                                                 const int* __restrict__ src_csr,
                                                 const float* __restrict__ dis,
                                                 const float* __restrict__ b3,
                                                 float* __restrict__ out, int nN) {
    int i = blockIdx.x * 256 + threadIdx.x;
    if (i >= nN) return;
    float acc = hw3s[i];
    int beg = row_ptr[i], end = row_ptr[i + 1];
    for (int e = beg; e < end; ++e) acc += hw3s[src_csr[e]];
    out[i] = fmaxf(acc * dis[i] + b3[0], 0.f);
}

extern "C" void kernel_launch(void* const* d_in, const int* in_sizes, int n_in,
                              void* d_out, int out_size, void* d_ws, size_t ws_size,
                              hipStream_t stream) {
    const float* x  = (const float*)d_in[0];
    const int*   ei = (const int*)d_in[1];
    const float* W1 = (const float*)d_in[2];
    const float* b1 = (const float*)d_in[3];
    const float* W2 = (const float*)d_in[4];
    const float* b2 = (const float*)d_in[5];
    const float* W3 = (const float*)d_in[6];
    const float* b3 = (const float*)d_in[7];

    const int nN = in_sizes[0] / 128;
    const int nE = in_sizes[1] / 2;
    const int* src = ei;
    const int* dst = ei + nE;

    const int nB = (nN + 255) / 256;   // scan blocks (<=256)

    // workspace layout
    char* p = (char*)d_ws;
    int*    cnt8     = (int*)p;           p += (size_t)nN * 8 * 4;
    int*    base8    = (int*)p;           p += (size_t)nN * 8 * 4;
    int*    excl     = (int*)p;           p += (size_t)nN * 4;
    int*    blk_sum  = (int*)p;           p += (size_t)(nB + 1) * 4;
    int*    row_ptr  = (int*)p;           p += (size_t)(nN + 1) * 4;
    int*    rank     = (int*)p;           p += (size_t)nE * 4;
    int*    src_csr  = (int*)p;           p += (size_t)nE * 4;
    float*  dis      = (float*)p;         p += (size_t)nN * 4;
    float*  hw3s     = (float*)p;         p += (size_t)nN * 4;
    p = (char*)(((uintptr_t)p + 255) & ~(uintptr_t)255);
    __half* Wt1      = (__half*)p;        p += (size_t)128 * 128 * 2;
    __half* Wt2      = (__half*)p;        p += (size_t)128 * 128 * 2;
    __half* bufA     = (__half*)p;        p += (size_t)nN * 128 * 2;  // HWS1
    p = (char*)(((uintptr_t)p + 255) & ~(uintptr_t)255);
    __half* bufB     = (__half*)p;        p += (size_t)nN * 128 * 2;  // HWS2

    const int BE  = (nE + 255) / 256;            // 2344
    const int BN  = (nN + 255) / 256;            // 196
    const int BG  = (nN + 63) / 64;              // 782
    const int BGV = (nN + 15) / 16;              // 3125

    // --- CSR build + norms + weight cast (R17 structure, banked count) ---
    hipMemsetAsync(cnt8, 0, (size_t)nN * 8 * sizeof(int), stream);
    k_count_wcast<<<BE + 64, 256, 0, stream>>>(dst, cnt8, rank, nE, BE, nN,
                                               W1, W2, Wt1, Wt2);
    k_scan_blk<<<nB, 256, 0, stream>>>(cnt8, dis, excl, blk_sum, nN);
    k_scan_add<<<nB, 256, 0, stream>>>(excl, blk_sum, cnt8, row_ptr, base8, nN, nB);

    // --- layer-1 GEMM (blocks [0,BG)) overlapped with atomic-free binning ---
    k_gemm_bin<<<BG + BE, 256, 0, stream>>>(x, Wt1, dis, bufA, nN, BG,
                                            src, dst, rank, base8, src_csr, nE);

    // --- fused layer-1 gather + layer-2 GEMM: HWS1 -> HWS2 (512 thr) ---
    k_gather_gemm<<<BG, 512, 0, stream>>>(bufA, row_ptr, src_csr, dis, b1, Wt2,
                                          bufB, nN);

    // --- fused layer-2 gather + layer-3 gemv: HWS2 -> hw3s ---
    k_gather_gemv<<<BGV, 256, 0, stream>>>(bufB, row_ptr, src_csr, dis, b2, W3,
                                           hw3s, nN);

    // --- layer-3 scalar gather -> d_out ---
    k_gather3<<<BN, 256, 0, stream>>>(hw3s, row_ptr, src_csr, dis, b3,
                                      (float*)d_out, nN);
}